// Round 4
// baseline (241.704 us; speedup 1.0000x reference)
//
#include <hip/hip_runtime.h>
#include <hip/hip_cooperative_groups.h>
#include <stdint.h>

namespace cg = cooperative_groups;

// Problem constants (fixed by reference file)
#define N_NODES 50000
#define KDEG    16
#define NFEAT   128
#define NTPL    16
#define MTPL    8
#define NTILES  ((N_NODES + 63) / 64)

// Workspace layout (floats):
//   [0    .. 2047]  tmean[t*128 + f]
//   [2048 .. 2063]  tsq[t]
//   [2064 .. 2079]  mCt[t]
//   [2080 .. 2095]  mCt2[t]
//   [2112 .. ]      z[n*16 + t] = 0.5*s2[n] - x[n]·tmean_t
#define TMEAN_OFF 0
#define TSQ_OFF   2048
#define MCT_OFF   2064
#define MCT2_OFF  2080
#define Z_OFF     2112
#define WS_FLOATS (Z_OFF + N_NODES * NTPL)
#define WS_BYTES  ((size_t)WS_FLOATS * 4)

__global__ __launch_bounds__(256, 4)
void ltfwg_fused(const float* __restrict__ x,     // [N,128]
                 const int* __restrict__ dst,     // [N,16]
                 const float* __restrict__ tmpl,  // [16,8,8]
                 const float* __restrict__ tfeat, // [16,8,128]
                 float* __restrict__ ws,
                 float* __restrict__ out) {       // [N,16]
    cg::grid_group grid = cg::this_grid();
    const int tid  = threadIdx.x;
    const int lane = tid & 63;

    __shared__ float tm_lds[NTPL * 144];  // [t][q][36] skewed: conflict-free
    __shared__ float red[128];

    // ================= phase 0: template stats (blocks 0..15) =================
    if (blockIdx.x < NTPL) {
        const int t = blockIdx.x;
        if (tid < 128) {
            float s = 0.f, ssq = 0.f;
            #pragma unroll
            for (int m = 0; m < MTPL; ++m) {
                float v = tfeat[t * (MTPL * NFEAT) + m * NFEAT + tid];
                s += v;
                ssq += v * v;
            }
            ws[TMEAN_OFF + t * NFEAT + tid] = s * 0.125f;
            red[tid] = ssq;
        }
        __syncthreads();
        if (tid < 64) {
            float v = red[tid] + red[tid + 64];
            #pragma unroll
            for (int off = 32; off >= 1; off >>= 1) v += __shfl_xor(v, off);
            if (tid == 0) ws[TSQ_OFF + t] = v * 0.125f;

            float w0 = tmpl[t * 64 + tid];
            float sv = w0, sv2 = w0 * w0;
            #pragma unroll
            for (int off = 32; off >= 1; off >>= 1) {
                sv  += __shfl_xor(sv, off);
                sv2 += __shfl_xor(sv2, off);
            }
            if (tid == 0) {
                ws[MCT_OFF + t]  = sv  * (1.f / 64.f);
                ws[MCT2_OFF + t] = sv2 * (1.f / 64.f);
            }
        }
    }
    grid.sync();

    // ================= phase 1: z[n][t] = 0.5*s2 - x·tmean ====================
    // Stage tmean into LDS, skewed layout [t][q][36] so quad lanes hit
    // distinct banks: bank(t*144 + q*36 + 4j) = (16t + 4q + 4j) % 32.
    {
        const int base = tid * 8;  // 2048 floats, 8 per thread
        #pragma unroll
        for (int k = 0; k < 8; ++k) {
            int g = base + k;
            int t = g >> 7, r = g & 127;
            tm_lds[t * 144 + (r >> 5) * 36 + (r & 31)] = ws[TMEAN_OFF + g];
        }
    }
    __syncthreads();

    const int q  = tid & 3;        // feature quarter (32 feats)
    const int rr = tid >> 2;       // row within 64-row tile
    for (int tile = blockIdx.x; tile < NTILES; tile += gridDim.x) {
        int n = tile * 64 + rr;
        if (n < N_NODES) {
            const float4* x4 = (const float4*)x + (size_t)n * 32 + q * 8;
            float4 xv[8];
            #pragma unroll
            for (int j = 0; j < 8; ++j) xv[j] = x4[j];

            float s2 = 0.f;
            #pragma unroll
            for (int j = 0; j < 8; ++j)
                s2 += xv[j].x * xv[j].x + xv[j].y * xv[j].y +
                      xv[j].z * xv[j].z + xv[j].w * xv[j].w;

            float acc[NTPL];
            #pragma unroll
            for (int t = 0; t < NTPL; ++t) {
                const float* tb = tm_lds + t * 144 + q * 36;
                float a = 0.f;
                #pragma unroll
                for (int j = 0; j < 8; ++j) {
                    float4 tv = *(const float4*)(tb + 4 * j);
                    a += xv[j].x * tv.x + xv[j].y * tv.y +
                         xv[j].z * tv.z + xv[j].w * tv.w;
                }
                acc[t] = a;
            }

            // combine across the quad (q-mates): all 4 lanes end with totals
            float h = s2;
            h += __shfl_xor(h, 1);
            h += __shfl_xor(h, 2);
            h *= 0.5f;
            #pragma unroll
            for (int t = 0; t < NTPL; ++t) {
                acc[t] += __shfl_xor(acc[t], 1);
                acc[t] += __shfl_xor(acc[t], 2);
            }
            // lane q writes chunk q of the row: fully coalesced 4KB/wave
            float b0, b1, b2, b3;
            if (q == 0)      { b0 = acc[0];  b1 = acc[1];  b2 = acc[2];  b3 = acc[3];  }
            else if (q == 1) { b0 = acc[4];  b1 = acc[5];  b2 = acc[6];  b3 = acc[7];  }
            else if (q == 2) { b0 = acc[8];  b1 = acc[9];  b2 = acc[10]; b3 = acc[11]; }
            else             { b0 = acc[12]; b1 = acc[13]; b2 = acc[14]; b3 = acc[15]; }
            float4 zz = make_float4(h - b0, h - b1, h - b2, h - b3);
            ((float4*)(ws + Z_OFF))[(size_t)n * 4 + q] = zz;
        }
    }
    grid.sync();

    // ================= phase 2: gather + structure (R3-proven logic) ==========
    const int gwave  = (blockIdx.x * blockDim.x + tid) >> 6;
    const int nwaves = (gridDim.x * blockDim.x) >> 6;

    const int tl = ((lane >> 4) << 2) + (lane & 3);
    const float A  = 0.5f * (ws[TSQ_OFF + tl] + ws[MCT2_OFF + tl]);
    const float Bc = 0.5f - ws[MCT_OFF + tl];
    const bool writer = (lane & 15) < 4;
    const float4* z4 = (const float4*)(ws + Z_OFF);

    for (int n = gwave; n < N_NODES; n += nwaves) {
        const int nbr = dst[n * KDEG + (lane & 15)];         // a = lane&15

        float4 v = z4[(size_t)nbr * 4 + (lane >> 4)];        // 16 rows x 64B

        int nida = __shfl(nbr, lane >> 2);                   // a' = lane>>2
        int4 cv = ((const int4*)(dst + (size_t)nida * KDEG))[lane & 3];
        uint32_t m = 0;
        #pragma unroll
        for (int b = 0; b < KDEG; ++b) {
            int vb = __builtin_amdgcn_readlane(nbr, b);
            uint32_t hit = (uint32_t)((cv.x == vb) | (cv.y == vb) |
                                      (cv.z == vb) | (cv.w == vb));
            m |= hit << b;
        }
        m |= (uint32_t)__shfl_xor((int)m, 1);
        m |= (uint32_t)__shfl_xor((int)m, 2);
        int cm = __popc(m);
        cm += __shfl_xor(cm, 4);
        cm += __shfl_xor(cm, 8);
        cm += __shfl_xor(cm, 16);
        cm += __shfl_xor(cm, 32);

        float v0 = v.x, v1 = v.y, v2 = v.z, v3 = v.w;
        #pragma unroll
        for (int off = 1; off <= 8; off <<= 1) {
            v0 += __shfl_xor(v0, off);
            v1 += __shfl_xor(v1, off);
            v2 += __shfl_xor(v2, off);
            v3 += __shfl_xor(v3, off);
        }

        if (writer) {
            int j = lane & 3;
            float dsel = (j == 0) ? v0 : (j == 1) ? v1 : (j == 2) ? v2 : v3;
            float val = 0.0625f * dsel + A + (float)cm * (1.f / 256.f) * Bc;
            out[n * NTPL + tl] = val;
        }
    }
}

// ---------------- fallback path (proven R2 kernels) ----------------
__global__ void ltfwg_prep(const float* __restrict__ tmpl,
                           const float* __restrict__ tfeat,
                           float* __restrict__ ws) {
    const int t   = blockIdx.x;
    const int tid = threadIdx.x;
    float s = 0.f, ssq = 0.f;
    #pragma unroll
    for (int m = 0; m < MTPL; ++m) {
        float v = tfeat[t * (MTPL * NFEAT) + m * NFEAT + tid];
        s += v;
        ssq += v * v;
    }
    ws[TMEAN_OFF + t * NFEAT + tid] = s * 0.125f;
    __shared__ float red[128];
    red[tid] = ssq;
    __syncthreads();
    for (int o = 64; o > 0; o >>= 1) {
        if (tid < o) red[tid] += red[tid + o];
        __syncthreads();
    }
    if (tid == 0) ws[TSQ_OFF + t] = red[0] * 0.125f;
    if (tid < 64) {
        float v = tmpl[t * 64 + tid];
        float sv = v, sv2 = v * v;
        #pragma unroll
        for (int off = 32; off >= 1; off >>= 1) {
            sv  += __shfl_xor(sv, off);
            sv2 += __shfl_xor(sv2, off);
        }
        if (tid == 0) {
            ws[MCT_OFF + t]  = sv  * (1.f / 64.f);
            ws[MCT2_OFF + t] = sv2 * (1.f / 64.f);
        }
    }
}

__global__ __launch_bounds__(256, 4)
void ltfwg_fallback(const float* __restrict__ x, const int* __restrict__ dst,
                    const float* __restrict__ ws, float* __restrict__ out) {
    const int lane   = threadIdx.x & 63;
    const int wave   = (blockIdx.x * blockDim.x + threadIdx.x) >> 6;
    const int nwaves = (gridDim.x * blockDim.x) >> 6;
    float tm0[NTPL], tm1[NTPL];
    #pragma unroll
    for (int t = 0; t < NTPL; ++t) {
        float2 tv = ((const float2*)(ws + TMEAN_OFF + t * NFEAT))[lane];
        tm0[t] = tv.x;
        tm1[t] = tv.y;
    }
    const int tl = lane & 15;
    const float A  = 0.5f * (ws[TSQ_OFF + tl] + ws[MCT2_OFF + tl]);
    const float Bc = 0.5f - ws[MCT_OFF + tl];
    for (int n = wave; n < N_NODES; n += nwaves) {
        const int nbr = dst[n * KDEG + (lane & 15)];
        float fs0 = 0.f, fs1 = 0.f, sqa = 0.f;
        #pragma unroll
        for (int a = 0; a < KDEG; ++a) {
            int nid = __shfl(nbr, a);
            float2 fv = ((const float2*)x)[nid * (NFEAT / 2) + lane];
            fs0 += fv.x; fs1 += fv.y;
            sqa += fv.x * fv.x + fv.y * fv.y;
        }
        float dotp[NTPL];
        #pragma unroll
        for (int t = 0; t < NTPL; ++t) dotp[t] = fs0 * tm0[t] + fs1 * tm1[t];
        int nida = __shfl(nbr, lane >> 2);
        int4 cv = ((const int4*)(dst + nida * KDEG))[lane & 3];
        uint32_t m = 0;
        #pragma unroll
        for (int b = 0; b < KDEG; ++b) {
            int vb = __shfl(nbr, b);
            uint32_t hit = (uint32_t)((cv.x == vb) | (cv.y == vb) |
                                      (cv.z == vb) | (cv.w == vb));
            m |= hit << b;
        }
        m |= (uint32_t)__shfl_xor((int)m, 1);
        m |= (uint32_t)__shfl_xor((int)m, 2);
        float cnt = (float)__popc(m);
        #pragma unroll
        for (int off = 32; off >= 1; off >>= 1) {
            sqa += __shfl_xor(sqa, off);
            cnt += __shfl_xor(cnt, off);
            #pragma unroll
            for (int t = 0; t < NTPL; ++t) dotp[t] += __shfl_xor(dotp[t], off);
        }
        float dsel = dotp[0];
        #pragma unroll
        for (int t = 1; t < NTPL; ++t) dsel = (lane == t) ? dotp[t] : dsel;
        if (lane < NTPL) {
            float mC = cnt * (1.0f / 1024.0f);
            out[n * NTPL + lane] = 0.03125f * sqa - 0.0625f * dsel + A + mC * Bc;
        }
    }
}

extern "C" void kernel_launch(void* const* d_in, const int* in_sizes, int n_in,
                              void* d_out, int out_size, void* d_ws, size_t ws_size,
                              hipStream_t stream) {
    const float* x     = (const float*)d_in[0];
    const int*   edge  = (const int*)d_in[1];
    const float* tmpl  = (const float*)d_in[2];
    const float* tfeat = (const float*)d_in[3];
    float* ws  = (float*)d_ws;
    float* out = (float*)d_out;
    const int* dst = edge + (N_NODES * KDEG);

    bool coop_ok = false;
    int grid = 0;
    if (ws_size >= WS_BYTES) {
        int dev = 0, coop = 0, ncu = 0, maxb = 0;
        if (hipGetDevice(&dev) == hipSuccess &&
            hipDeviceGetAttribute(&coop, hipDeviceAttributeCooperativeLaunch, dev) == hipSuccess &&
            coop &&
            hipDeviceGetAttribute(&ncu, hipDeviceAttributeMultiprocessorCount, dev) == hipSuccess &&
            hipOccupancyMaxActiveBlocksPerMultiprocessor(&maxb, (const void*)ltfwg_fused, 256, 0) == hipSuccess &&
            maxb >= 1) {
            grid = maxb * ncu;
            if (grid > 1024) grid = 1024;
            if (grid >= NTPL) coop_ok = true;
        }
    }

    if (coop_ok) {
        void* args[] = {(void*)&x, (void*)&dst, (void*)&tmpl, (void*)&tfeat,
                        (void*)&ws, (void*)&out};
        hipError_t e = hipLaunchCooperativeKernel((const void*)ltfwg_fused,
                                                  dim3(grid), dim3(256),
                                                  args, 0, stream);
        if (e == hipSuccess) return;
    }

    // fallback: proven 2-kernel path
    ltfwg_prep<<<NTPL, 128, 0, stream>>>(tmpl, tfeat, ws);
    ltfwg_fallback<<<1024, 256, 0, stream>>>(x, dst, ws, out);
}

// Round 5
// 110.390 us; speedup vs baseline: 2.1895x; 2.1895x over previous
//
#include <hip/hip_runtime.h>
#include <stdint.h>

// Problem constants (fixed by reference file)
#define N_NODES 50000
#define KDEG    16
#define NFEAT   128
#define NTPL    16
#define MTPL    8
#define NTILES  ((N_NODES + 63) / 64)

// Workspace layout (floats):
//   [0    .. 2047]  tmean[t*128 + f]        (fallback path only)
//   [2048 .. 2063]  tsq[t]
//   [2064 .. 2079]  mCt[t]
//   [2080 .. 2095]  mCt2[t]
//   [2112 .. ]      z[n*16 + t] = 0.5*s2[n] - x[n]·tmean_t
#define TMEAN_OFF 0
#define TSQ_OFF   2048
#define MCT_OFF   2064
#define MCT2_OFF  2080
#define Z_OFF     2112
#define WS_FLOATS (Z_OFF + N_NODES * NTPL)
#define WS_BYTES  ((size_t)WS_FLOATS * 4)

// ============ Kernel A: template stats (per-block, redundant) + z table ======
__global__ __launch_bounds__(256, 4)
void ltfwg_zbuild(const float* __restrict__ x,      // [N,128]
                  const float* __restrict__ tmpl,   // [16,8,8]
                  const float* __restrict__ tfeat,  // [16,8,128]
                  float* __restrict__ ws) {
    const int tid = threadIdx.x;

    // tmean in LDS, skewed [t][q][36]: bank(t*144+q*36+4j) = (16t+4q+4j)%32
    __shared__ float tm_lds[NTPL * 144];

    if (tid < 128) {
        #pragma unroll
        for (int t = 0; t < NTPL; ++t) {
            float s = 0.f;
            #pragma unroll
            for (int m = 0; m < MTPL; ++m)
                s += tfeat[t * (MTPL * NFEAT) + m * NFEAT + tid];
            tm_lds[t * 144 + (tid >> 5) * 36 + (tid & 31)] = s * 0.125f;
        }
    }

    // Block 0 additionally computes the 48 scalar stats kernel B needs.
    if (blockIdx.x == 0) {
        const int t = tid >> 4;      // 16 threads per template
        const int j = tid & 15;
        // tsq: mean over rows of (sum over feats of v^2) = sum(v^2)/8
        float ssq = 0.f;
        #pragma unroll
        for (int m = 0; m < MTPL; ++m)
            #pragma unroll
            for (int c = 0; c < 8; ++c) {
                float v = tfeat[t * (MTPL * NFEAT) + m * NFEAT + j * 8 + c];
                ssq += v * v;
            }
        // templates: thread j covers 4 of 64 entries
        float sv = 0.f, sv2 = 0.f;
        #pragma unroll
        for (int c = 0; c < 4; ++c) {
            float v = tmpl[t * 64 + j * 4 + c];
            sv += v;
            sv2 += v * v;
        }
        #pragma unroll
        for (int off = 1; off <= 8; off <<= 1) {  // reduce within 16-lane group
            ssq += __shfl_xor(ssq, off);
            sv  += __shfl_xor(sv, off);
            sv2 += __shfl_xor(sv2, off);
        }
        if (j == 0) {
            ws[TSQ_OFF + t]  = ssq * 0.125f;
            ws[MCT_OFF + t]  = sv  * (1.f / 64.f);
            ws[MCT2_OFF + t] = sv2 * (1.f / 64.f);
        }
    }
    __syncthreads();

    // z phase: 4 lanes per row (q = feature quarter), 64 rows per tile
    const int q  = tid & 3;
    const int rr = tid >> 2;
    for (int tile = blockIdx.x; tile < NTILES; tile += gridDim.x) {
        int n = tile * 64 + rr;
        if (n < N_NODES) {
            const float4* x4 = (const float4*)x + (size_t)n * 32 + q * 8;
            float4 xv[8];
            #pragma unroll
            for (int jj = 0; jj < 8; ++jj) xv[jj] = x4[jj];

            float s2 = 0.f;
            #pragma unroll
            for (int jj = 0; jj < 8; ++jj)
                s2 += xv[jj].x * xv[jj].x + xv[jj].y * xv[jj].y +
                      xv[jj].z * xv[jj].z + xv[jj].w * xv[jj].w;

            float acc[NTPL];
            #pragma unroll
            for (int t = 0; t < NTPL; ++t) {
                const float* tb = tm_lds + t * 144 + q * 36;
                float a = 0.f;
                #pragma unroll
                for (int jj = 0; jj < 8; ++jj) {
                    float4 tv = *(const float4*)(tb + 4 * jj);
                    a += xv[jj].x * tv.x + xv[jj].y * tv.y +
                         xv[jj].z * tv.z + xv[jj].w * tv.w;
                }
                acc[t] = a;
            }

            float h = s2;
            h += __shfl_xor(h, 1);
            h += __shfl_xor(h, 2);
            h *= 0.5f;
            #pragma unroll
            for (int t = 0; t < NTPL; ++t) {
                acc[t] += __shfl_xor(acc[t], 1);
                acc[t] += __shfl_xor(acc[t], 2);
            }
            float b0, b1, b2, b3;
            if (q == 0)      { b0 = acc[0];  b1 = acc[1];  b2 = acc[2];  b3 = acc[3];  }
            else if (q == 1) { b0 = acc[4];  b1 = acc[5];  b2 = acc[6];  b3 = acc[7];  }
            else if (q == 2) { b0 = acc[8];  b1 = acc[9];  b2 = acc[10]; b3 = acc[11]; }
            else             { b0 = acc[12]; b1 = acc[13]; b2 = acc[14]; b3 = acc[15]; }
            float4 zz = make_float4(h - b0, h - b1, h - b2, h - b3);
            ((float4*)(ws + Z_OFF))[(size_t)n * 4 + q] = zz;
        }
    }
}

// ============ Kernel B: per-node gather + structure (R3-proven logic) ========
__global__ __launch_bounds__(256, 8)
void ltfwg_gather(const int* __restrict__ dst, const float* __restrict__ ws,
                  float* __restrict__ out) {
    const int lane   = threadIdx.x & 63;
    const int gwave  = (blockIdx.x * blockDim.x + threadIdx.x) >> 6;
    const int nwaves = (gridDim.x * blockDim.x) >> 6;

    const int tl = ((lane >> 4) << 2) + (lane & 3);
    const float A  = 0.5f * (ws[TSQ_OFF + tl] + ws[MCT2_OFF + tl]);
    const float Bc = 0.5f - ws[MCT_OFF + tl];
    const bool writer = (lane & 15) < 4;
    const float4* z4 = (const float4*)(ws + Z_OFF);

    int n = gwave;
    int nbr = (n < N_NODES) ? dst[n * KDEG + (lane & 15)] : 0;
    while (n < N_NODES) {
        const int n2 = n + nwaves;
        int nbr_next = (n2 < N_NODES) ? dst[n2 * KDEG + (lane & 15)] : 0;

        float4 v = z4[(size_t)nbr * 4 + (lane >> 4)];        // 16 rows x 64B

        int nida = __shfl(nbr, lane >> 2);                   // a' = lane>>2
        int4 cv = ((const int4*)(dst + (size_t)nida * KDEG))[lane & 3];
        uint32_t m = 0;
        #pragma unroll
        for (int b = 0; b < KDEG; ++b) {
            int vb = __builtin_amdgcn_readlane(nbr, b);
            uint32_t hit = (uint32_t)((cv.x == vb) | (cv.y == vb) |
                                      (cv.z == vb) | (cv.w == vb));
            m |= hit << b;
        }
        m |= (uint32_t)__shfl_xor((int)m, 1);
        m |= (uint32_t)__shfl_xor((int)m, 2);
        int cm = __popc(m);
        cm += __shfl_xor(cm, 4);
        cm += __shfl_xor(cm, 8);
        cm += __shfl_xor(cm, 16);
        cm += __shfl_xor(cm, 32);

        float v0 = v.x, v1 = v.y, v2 = v.z, v3 = v.w;
        #pragma unroll
        for (int off = 1; off <= 8; off <<= 1) {
            v0 += __shfl_xor(v0, off);
            v1 += __shfl_xor(v1, off);
            v2 += __shfl_xor(v2, off);
            v3 += __shfl_xor(v3, off);
        }

        if (writer) {
            int j = lane & 3;
            float dsel = (j == 0) ? v0 : (j == 1) ? v1 : (j == 2) ? v2 : v3;
            float val = 0.0625f * dsel + A + (float)cm * (1.f / 256.f) * Bc;
            out[n * NTPL + tl] = val;
        }
        n = n2;
        nbr = nbr_next;
    }
}

// ---------------- fallback path (proven R2 kernels, ws too small) ------------
__global__ void ltfwg_prep(const float* __restrict__ tmpl,
                           const float* __restrict__ tfeat,
                           float* __restrict__ ws) {
    const int t   = blockIdx.x;
    const int tid = threadIdx.x;
    float s = 0.f, ssq = 0.f;
    #pragma unroll
    for (int m = 0; m < MTPL; ++m) {
        float v = tfeat[t * (MTPL * NFEAT) + m * NFEAT + tid];
        s += v;
        ssq += v * v;
    }
    ws[TMEAN_OFF + t * NFEAT + tid] = s * 0.125f;
    __shared__ float red[128];
    red[tid] = ssq;
    __syncthreads();
    for (int o = 64; o > 0; o >>= 1) {
        if (tid < o) red[tid] += red[tid + o];
        __syncthreads();
    }
    if (tid == 0) ws[TSQ_OFF + t] = red[0] * 0.125f;
    if (tid < 64) {
        float v = tmpl[t * 64 + tid];
        float sv = v, sv2 = v * v;
        #pragma unroll
        for (int off = 32; off >= 1; off >>= 1) {
            sv  += __shfl_xor(sv, off);
            sv2 += __shfl_xor(sv2, off);
        }
        if (tid == 0) {
            ws[MCT_OFF + t]  = sv  * (1.f / 64.f);
            ws[MCT2_OFF + t] = sv2 * (1.f / 64.f);
        }
    }
}

__global__ __launch_bounds__(256, 4)
void ltfwg_fallback(const float* __restrict__ x, const int* __restrict__ dst,
                    const float* __restrict__ ws, float* __restrict__ out) {
    const int lane   = threadIdx.x & 63;
    const int wave   = (blockIdx.x * blockDim.x + threadIdx.x) >> 6;
    const int nwaves = (gridDim.x * blockDim.x) >> 6;
    float tm0[NTPL], tm1[NTPL];
    #pragma unroll
    for (int t = 0; t < NTPL; ++t) {
        float2 tv = ((const float2*)(ws + TMEAN_OFF + t * NFEAT))[lane];
        tm0[t] = tv.x;
        tm1[t] = tv.y;
    }
    const int tl = lane & 15;
    const float A  = 0.5f * (ws[TSQ_OFF + tl] + ws[MCT2_OFF + tl]);
    const float Bc = 0.5f - ws[MCT_OFF + tl];
    for (int n = wave; n < N_NODES; n += nwaves) {
        const int nbr = dst[n * KDEG + (lane & 15)];
        float fs0 = 0.f, fs1 = 0.f, sqa = 0.f;
        #pragma unroll
        for (int a = 0; a < KDEG; ++a) {
            int nid = __shfl(nbr, a);
            float2 fv = ((const float2*)x)[nid * (NFEAT / 2) + lane];
            fs0 += fv.x; fs1 += fv.y;
            sqa += fv.x * fv.x + fv.y * fv.y;
        }
        float dotp[NTPL];
        #pragma unroll
        for (int t = 0; t < NTPL; ++t) dotp[t] = fs0 * tm0[t] + fs1 * tm1[t];
        int nida = __shfl(nbr, lane >> 2);
        int4 cv = ((const int4*)(dst + nida * KDEG))[lane & 3];
        uint32_t m = 0;
        #pragma unroll
        for (int b = 0; b < KDEG; ++b) {
            int vb = __shfl(nbr, b);
            uint32_t hit = (uint32_t)((cv.x == vb) | (cv.y == vb) |
                                      (cv.z == vb) | (cv.w == vb));
            m |= hit << b;
        }
        m |= (uint32_t)__shfl_xor((int)m, 1);
        m |= (uint32_t)__shfl_xor((int)m, 2);
        float cnt = (float)__popc(m);
        #pragma unroll
        for (int off = 32; off >= 1; off >>= 1) {
            sqa += __shfl_xor(sqa, off);
            cnt += __shfl_xor(cnt, off);
            #pragma unroll
            for (int t = 0; t < NTPL; ++t) dotp[t] += __shfl_xor(dotp[t], off);
        }
        float dsel = dotp[0];
        #pragma unroll
        for (int t = 1; t < NTPL; ++t) dsel = (lane == t) ? dotp[t] : dsel;
        if (lane < NTPL) {
            float mC = cnt * (1.0f / 1024.0f);
            out[n * NTPL + lane] = 0.03125f * sqa - 0.0625f * dsel + A + mC * Bc;
        }
    }
}

extern "C" void kernel_launch(void* const* d_in, const int* in_sizes, int n_in,
                              void* d_out, int out_size, void* d_ws, size_t ws_size,
                              hipStream_t stream) {
    const float* x     = (const float*)d_in[0];
    const int*   edge  = (const int*)d_in[1];
    const float* tmpl  = (const float*)d_in[2];
    const float* tfeat = (const float*)d_in[3];
    float* ws  = (float*)d_ws;
    float* out = (float*)d_out;
    const int* dst = edge + (N_NODES * KDEG);

    if (ws_size >= WS_BYTES) {
        ltfwg_zbuild<<<256, 256, 0, stream>>>(x, tmpl, tfeat, ws);
        ltfwg_gather<<<2048, 256, 0, stream>>>(dst, ws, out);
    } else {
        ltfwg_prep<<<NTPL, 128, 0, stream>>>(tmpl, tfeat, ws);
        ltfwg_fallback<<<1024, 256, 0, stream>>>(x, dst, ws, out);
    }
}

// Round 6
// 104.660 us; speedup vs baseline: 2.3094x; 1.0547x over previous
//
#include <hip/hip_runtime.h>
#include <stdint.h>

// Problem constants (fixed by reference file)
#define N_NODES 50000
#define KDEG    16
#define NFEAT   128
#define NTPL    16
#define MTPL    8
#define NTILES  ((N_NODES + 63) / 64)

// Workspace layout (floats):
//   [0    .. 2047]  tmean[t*128 + f]        (fallback path only)
//   [2048 .. 2063]  tsq[t]
//   [2064 .. 2079]  mCt[t]
//   [2080 .. 2095]  mCt2[t]
//   [2112 .. ]      z[n*16 + t] = 0.5*s2[n] - x[n]·tmean_t
#define TMEAN_OFF 0
#define TSQ_OFF   2048
#define MCT_OFF   2064
#define MCT2_OFF  2080
#define Z_OFF     2112
#define WS_FLOATS (Z_OFF + N_NODES * NTPL)
#define WS_BYTES  ((size_t)WS_FLOATS * 4)

// ============ Kernel A: template stats (per-block, redundant) + z table ======
__global__ __launch_bounds__(256, 4)
void ltfwg_zbuild(const float* __restrict__ x,      // [N,128]
                  const float* __restrict__ tmpl,   // [16,8,8]
                  const float* __restrict__ tfeat,  // [16,8,128]
                  float* __restrict__ ws) {
    const int tid = threadIdx.x;

    // tmean in LDS, skewed [t][q][36]: bank(t*144+q*36+4j) = (16t+4q+4j)%32
    __shared__ float tm_lds[NTPL * 144];

    {   // all 256 threads: thread (f = tid&127, half = tid>>7) does 8 templates
        const int f  = tid & 127;
        const int t0 = (tid >> 7) * 8;
        #pragma unroll
        for (int k = 0; k < 8; ++k) {
            int t = t0 + k;
            float s = 0.f;
            #pragma unroll
            for (int m = 0; m < MTPL; ++m)
                s += tfeat[t * (MTPL * NFEAT) + m * NFEAT + f];
            tm_lds[t * 144 + (f >> 5) * 36 + (f & 31)] = s * 0.125f;
        }
    }

    // Block 0 additionally computes the 48 scalar stats kernel B needs.
    if (blockIdx.x == 0) {
        const int t = tid >> 4;      // 16 threads per template
        const int j = tid & 15;
        float ssq = 0.f;
        #pragma unroll
        for (int m = 0; m < MTPL; ++m)
            #pragma unroll
            for (int c = 0; c < 8; ++c) {
                float v = tfeat[t * (MTPL * NFEAT) + m * NFEAT + j * 8 + c];
                ssq += v * v;
            }
        float sv = 0.f, sv2 = 0.f;
        #pragma unroll
        for (int c = 0; c < 4; ++c) {
            float v = tmpl[t * 64 + j * 4 + c];
            sv += v;
            sv2 += v * v;
        }
        #pragma unroll
        for (int off = 1; off <= 8; off <<= 1) {
            ssq += __shfl_xor(ssq, off);
            sv  += __shfl_xor(sv, off);
            sv2 += __shfl_xor(sv2, off);
        }
        if (j == 0) {
            ws[TSQ_OFF + t]  = ssq * 0.125f;
            ws[MCT_OFF + t]  = sv  * (1.f / 64.f);
            ws[MCT2_OFF + t] = sv2 * (1.f / 64.f);
        }
    }
    __syncthreads();

    // z phase: 4 lanes per row (q = feature quarter), 64 rows per tile
    const int q  = tid & 3;
    const int rr = tid >> 2;
    for (int tile = blockIdx.x; tile < NTILES; tile += gridDim.x) {
        int n = tile * 64 + rr;
        if (n < N_NODES) {
            const float4* x4 = (const float4*)x + (size_t)n * 32 + q * 8;
            float4 xv[8];
            #pragma unroll
            for (int jj = 0; jj < 8; ++jj) xv[jj] = x4[jj];

            float s2 = 0.f;
            #pragma unroll
            for (int jj = 0; jj < 8; ++jj)
                s2 += xv[jj].x * xv[jj].x + xv[jj].y * xv[jj].y +
                      xv[jj].z * xv[jj].z + xv[jj].w * xv[jj].w;

            float acc[NTPL];
            #pragma unroll
            for (int t = 0; t < NTPL; ++t) {
                const float* tb = tm_lds + t * 144 + q * 36;
                float a = 0.f;
                #pragma unroll
                for (int jj = 0; jj < 8; ++jj) {
                    float4 tv = *(const float4*)(tb + 4 * jj);
                    a += xv[jj].x * tv.x + xv[jj].y * tv.y +
                         xv[jj].z * tv.z + xv[jj].w * tv.w;
                }
                acc[t] = a;
            }

            float h = s2;
            h += __shfl_xor(h, 1);
            h += __shfl_xor(h, 2);
            h *= 0.5f;
            #pragma unroll
            for (int t = 0; t < NTPL; ++t) {
                acc[t] += __shfl_xor(acc[t], 1);
                acc[t] += __shfl_xor(acc[t], 2);
            }
            float b0, b1, b2, b3;
            if (q == 0)      { b0 = acc[0];  b1 = acc[1];  b2 = acc[2];  b3 = acc[3];  }
            else if (q == 1) { b0 = acc[4];  b1 = acc[5];  b2 = acc[6];  b3 = acc[7];  }
            else if (q == 2) { b0 = acc[8];  b1 = acc[9];  b2 = acc[10]; b3 = acc[11]; }
            else             { b0 = acc[12]; b1 = acc[13]; b2 = acc[14]; b3 = acc[15]; }
            float4 zz = make_float4(h - b0, h - b1, h - b2, h - b3);
            ((float4*)(ws + Z_OFF))[(size_t)n * 4 + q] = zz;
        }
    }
}

// ============ Kernel B: per-node gather + structure ==========================
// Lane mapping: a = lane&15 (neighbor slot), c = lane>>4 (16B chunk).
// Both the z-gather and the dst-row (cv) load use the lane's OWN nbr:
// no shuffle on the address path — z and cv loads issue independently.
__global__ __launch_bounds__(256, 8)
void ltfwg_gather(const int* __restrict__ dst, const float* __restrict__ ws,
                  float* __restrict__ out) {
    const int lane   = threadIdx.x & 63;
    const int gwave  = (blockIdx.x * blockDim.x + threadIdx.x) >> 6;
    const int nwaves = (gridDim.x * blockDim.x) >> 6;
    const int a = lane & 15;
    const int c = lane >> 4;

    const int tl = c * 4 + (lane & 3);
    const float A  = 0.5f * (ws[TSQ_OFF + tl] + ws[MCT2_OFF + tl]);
    const float Bc = 0.5f - ws[MCT_OFF + tl];
    const bool writer = (lane & 15) < 4;
    const float4* z4 = (const float4*)(ws + Z_OFF);
    const int4*  d4 = (const int4*)dst;

    int n = gwave;
    int nbr = (n < N_NODES) ? dst[n * KDEG + a] : 0;
    while (n < N_NODES) {
        const int n2 = n + nwaves;
        int nbr_next = (n2 < N_NODES) ? dst[n2 * KDEG + a] : 0;

        // independent loads: z chunk + dst-row chunk of this lane's neighbor
        float4 v  = z4[(size_t)nbr * 4 + c];
        int4   cv = d4[(size_t)nbr * 4 + c];

        // membership mask: bit b = any(cv == nbr_b), partial over this chunk
        uint32_t m = 0;
        #pragma unroll
        for (int b = 0; b < KDEG; ++b) {
            int vb = __builtin_amdgcn_readlane(nbr, b);
            uint32_t hit = (uint32_t)((cv.x == vb) | (cv.y == vb) |
                                      (cv.z == vb) | (cv.w == vb));
            m |= hit << b;
        }
        // merge the 4 chunks of row a (lanes differing in bits 4,5)
        m |= (uint32_t)__shfl_xor((int)m, 16);
        m |= (uint32_t)__shfl_xor((int)m, 32);
        int cm = __popc(m);                    // rowcount(a)
        cm += __shfl_xor(cm, 1);               // sum the 16 rows of this group
        cm += __shfl_xor(cm, 2);
        cm += __shfl_xor(cm, 4);
        cm += __shfl_xor(cm, 8);               // cm = sum over all 256 pairs

        // z reduction over a within each 16-lane group
        float v0 = v.x, v1 = v.y, v2 = v.z, v3 = v.w;
        #pragma unroll
        for (int off = 1; off <= 8; off <<= 1) {
            v0 += __shfl_xor(v0, off);
            v1 += __shfl_xor(v1, off);
            v2 += __shfl_xor(v2, off);
            v3 += __shfl_xor(v3, off);
        }

        if (writer) {
            int j = lane & 3;
            float dsel = (j == 0) ? v0 : (j == 1) ? v1 : (j == 2) ? v2 : v3;
            float val = 0.0625f * dsel + A + (float)cm * (1.f / 256.f) * Bc;
            out[n * NTPL + tl] = val;
        }
        n = n2;
        nbr = nbr_next;
    }
}

// ---------------- fallback path (proven R2 kernels, ws too small) ------------
__global__ void ltfwg_prep(const float* __restrict__ tmpl,
                           const float* __restrict__ tfeat,
                           float* __restrict__ ws) {
    const int t   = blockIdx.x;
    const int tid = threadIdx.x;
    float s = 0.f, ssq = 0.f;
    #pragma unroll
    for (int m = 0; m < MTPL; ++m) {
        float v = tfeat[t * (MTPL * NFEAT) + m * NFEAT + tid];
        s += v;
        ssq += v * v;
    }
    ws[TMEAN_OFF + t * NFEAT + tid] = s * 0.125f;
    __shared__ float red[128];
    red[tid] = ssq;
    __syncthreads();
    for (int o = 64; o > 0; o >>= 1) {
        if (tid < o) red[tid] += red[tid + o];
        __syncthreads();
    }
    if (tid == 0) ws[TSQ_OFF + t] = red[0] * 0.125f;
    if (tid < 64) {
        float v = tmpl[t * 64 + tid];
        float sv = v, sv2 = v * v;
        #pragma unroll
        for (int off = 32; off >= 1; off >>= 1) {
            sv  += __shfl_xor(sv, off);
            sv2 += __shfl_xor(sv2, off);
        }
        if (tid == 0) {
            ws[MCT_OFF + t]  = sv  * (1.f / 64.f);
            ws[MCT2_OFF + t] = sv2 * (1.f / 64.f);
        }
    }
}

__global__ __launch_bounds__(256, 4)
void ltfwg_fallback(const float* __restrict__ x, const int* __restrict__ dst,
                    const float* __restrict__ ws, float* __restrict__ out) {
    const int lane   = threadIdx.x & 63;
    const int wave   = (blockIdx.x * blockDim.x + threadIdx.x) >> 6;
    const int nwaves = (gridDim.x * blockDim.x) >> 6;
    float tm0[NTPL], tm1[NTPL];
    #pragma unroll
    for (int t = 0; t < NTPL; ++t) {
        float2 tv = ((const float2*)(ws + TMEAN_OFF + t * NFEAT))[lane];
        tm0[t] = tv.x;
        tm1[t] = tv.y;
    }
    const int tl = lane & 15;
    const float A  = 0.5f * (ws[TSQ_OFF + tl] + ws[MCT2_OFF + tl]);
    const float Bc = 0.5f - ws[MCT_OFF + tl];
    for (int n = wave; n < N_NODES; n += nwaves) {
        const int nbr = dst[n * KDEG + (lane & 15)];
        float fs0 = 0.f, fs1 = 0.f, sqa = 0.f;
        #pragma unroll
        for (int a = 0; a < KDEG; ++a) {
            int nid = __shfl(nbr, a);
            float2 fv = ((const float2*)x)[nid * (NFEAT / 2) + lane];
            fs0 += fv.x; fs1 += fv.y;
            sqa += fv.x * fv.x + fv.y * fv.y;
        }
        float dotp[NTPL];
        #pragma unroll
        for (int t = 0; t < NTPL; ++t) dotp[t] = fs0 * tm0[t] + fs1 * tm1[t];
        int nida = __shfl(nbr, lane >> 2);
        int4 cv = ((const int4*)(dst + nida * KDEG))[lane & 3];
        uint32_t m = 0;
        #pragma unroll
        for (int b = 0; b < KDEG; ++b) {
            int vb = __shfl(nbr, b);
            uint32_t hit = (uint32_t)((cv.x == vb) | (cv.y == vb) |
                                      (cv.z == vb) | (cv.w == vb));
            m |= hit << b;
        }
        m |= (uint32_t)__shfl_xor((int)m, 1);
        m |= (uint32_t)__shfl_xor((int)m, 2);
        float cnt = (float)__popc(m);
        #pragma unroll
        for (int off = 32; off >= 1; off >>= 1) {
            sqa += __shfl_xor(sqa, off);
            cnt += __shfl_xor(cnt, off);
            #pragma unroll
            for (int t = 0; t < NTPL; ++t) dotp[t] += __shfl_xor(dotp[t], off);
        }
        float dsel = dotp[0];
        #pragma unroll
        for (int t = 1; t < NTPL; ++t) dsel = (lane == t) ? dotp[t] : dsel;
        if (lane < NTPL) {
            float mC = cnt * (1.0f / 1024.0f);
            out[n * NTPL + lane] = 0.03125f * sqa - 0.0625f * dsel + A + mC * Bc;
        }
    }
}

extern "C" void kernel_launch(void* const* d_in, const int* in_sizes, int n_in,
                              void* d_out, int out_size, void* d_ws, size_t ws_size,
                              hipStream_t stream) {
    const float* x     = (const float*)d_in[0];
    const int*   edge  = (const int*)d_in[1];
    const float* tmpl  = (const float*)d_in[2];
    const float* tfeat = (const float*)d_in[3];
    float* ws  = (float*)d_ws;
    float* out = (float*)d_out;
    const int* dst = edge + (N_NODES * KDEG);

    if (ws_size >= WS_BYTES) {
        ltfwg_zbuild<<<NTILES, 256, 0, stream>>>(x, tmpl, tfeat, ws);
        ltfwg_gather<<<2048, 256, 0, stream>>>(dst, ws, out);
    } else {
        ltfwg_prep<<<NTPL, 128, 0, stream>>>(tmpl, tfeat, ws);
        ltfwg_fallback<<<1024, 256, 0, stream>>>(x, dst, ws, out);
    }
}